// Round 3
// baseline (208.830 us; speedup 1.0000x reference)
//
#include <hip/hip_runtime.h>
#include <math.h>

// DynamicRelationModeler: x=concat(img,txt) [512x512]; per r: a=x@Wl_r^T, b=x@Wr_r^T;
// h=a_i+b_j+b1_r; LN over H; s=relu(hn)@w2_r+b2_r; argmax/max over r; mask.
//
// Round-3 experiment: K3/K2 inner loops use packed fp32 (v_pk_add_f32 /
// v_pk_fma_f32, VOP3P) via inline asm to halve VALU instruction count per
// tuple-pair. Structure (staging, swizzle, barriers) identical to round 2.

typedef float v2f __attribute__((ext_vector_type(2)));

namespace {
constexpr size_t PLANE  = 512 * 512;            // 262144
constexpr size_t OFF_A   = 0;
constexpr size_t OFF_B   = OFF_A + 4 * PLANE;   // 1048576
constexpr size_t OFF_DOT = OFF_B + 4 * PLANE;   // 2097152
constexpr size_t OFF_S   = OFF_DOT + 8 * PLANE; // 4194304
constexpr size_t OFF_MA  = OFF_S + 8 * PLANE;   // 6291456
constexpr size_t OFF_QA  = OFF_MA + 2048;
constexpr size_t OFF_MB  = OFF_QA + 2048;
constexpr size_t OFF_QB  = OFF_MB + 2048;
constexpr size_t OFF_G   = OFF_QB + 2048;       // gamma [2048]
constexpr size_t OFF_BW  = OFF_G + 2048;        // (beta,w2) [2048][2]
}

// packed helpers: D = A + B ; D = fma(A, B, C) ; acc = fma(A, B, acc)
__device__ __forceinline__ v2f pk_add(v2f a, v2f b) {
  v2f d;
  asm("v_pk_add_f32 %0, %1, %2" : "=v"(d) : "v"(a), "v"(b));
  return d;
}
__device__ __forceinline__ v2f pk_fma(v2f a, v2f b, v2f c) {
  v2f d;
  asm("v_pk_fma_f32 %0, %1, %2, %3" : "=v"(d) : "v"(a), "v"(b), "v"(c));
  return d;
}
__device__ __forceinline__ void pk_fma_acc(v2f& acc, v2f a, v2f b) {
  asm("v_pk_fma_f32 %0, %1, %2, %0" : "+v"(acc) : "v"(a), "v"(b));
}

// ---------------- K0: input GEMM  C[n][4096] = x @ [Wl|Wr]^T ----------------
// grid 512 = 8 i-tiles x 64 col-tiles; block 256 (16x16 threads, 4x4 reg tile)
// (unchanged: control kernel for the pk experiment)
__global__ __launch_bounds__(256) void k0_gemm(const float* __restrict__ img,
                                               const float* __restrict__ txt,
                                               const float* __restrict__ W1,
                                               const float* __restrict__ b1,
                                               float* __restrict__ ws) {
  const int b = blockIdx.x;
  const int it = b >> 6;
  const int ct = b & 63;
  const int which = ct >> 5;      // 0 -> a (Wl), 1 -> b (Wr)
  const int r = (ct >> 3) & 3;
  const int ht = ct & 7;
  const int i0 = it << 6, h0 = ht << 6;
  const int t = threadIdx.x;
  const int tx = t & 15, ty = t >> 4;

  __shared__ float Xs[16 * 68];   // [k][i], pitch 68 -> 16B-aligned rows for b128 reads
  __shared__ float Wsm[16 * 68];  // [k][h]

  float acc[16], pacc[16];
#pragma unroll
  for (int p = 0; p < 16; ++p) { acc[p] = 0.f; pacc[p] = 0.f; }

  const int srow = t >> 2;
  const int sf4 = (t & 3) << 2;
  const int xi = i0 + srow;
  const float* xrow = (xi < 256) ? (img + (size_t)xi * 512)
                                 : (txt + (size_t)(xi - 256) * 512);
  const float* wrow = W1 + (size_t)(r * 512 + h0 + srow) * 1024 + which * 512;

  for (int k0 = 0; k0 < 512; k0 += 16) {
    const float4 xv = *(const float4*)(xrow + k0 + sf4);
    const float4 wv = *(const float4*)(wrow + k0 + sf4);
    __syncthreads();
    Xs[(sf4 + 0) * 68 + srow] = xv.x;
    Xs[(sf4 + 1) * 68 + srow] = xv.y;
    Xs[(sf4 + 2) * 68 + srow] = xv.z;
    Xs[(sf4 + 3) * 68 + srow] = xv.w;
    Wsm[(sf4 + 0) * 68 + srow] = wv.x;
    Wsm[(sf4 + 1) * 68 + srow] = wv.y;
    Wsm[(sf4 + 2) * 68 + srow] = wv.z;
    Wsm[(sf4 + 3) * 68 + srow] = wv.w;
    __syncthreads();
#pragma unroll
    for (int k = 0; k < 16; ++k) {
      const float4 a4 = *(const float4*)&Xs[k * 68 + 4 * ty];
      const float4 b4 = *(const float4*)&Wsm[k * 68 + 4 * tx];
      const float av[4] = {a4.x, a4.y, a4.z, a4.w};
      const float bv[4] = {b4.x, b4.y, b4.z, b4.w};
#pragma unroll
      for (int c = 0; c < 4; ++c)
#pragma unroll
        for (int d = 0; d < 4; ++d)
          pacc[c * 4 + d] = fmaf(av[c], bv[d], pacc[c * 4 + d]);
    }
    // fold per-stage partial into master (split accumulation: ~1e-7 error)
#pragma unroll
    for (int p = 0; p < 16; ++p) { acc[p] += pacc[p]; pacc[p] = 0.f; }
  }

  float4 bb = make_float4(0.f, 0.f, 0.f, 0.f);
  if (which) bb = *(const float4*)(b1 + r * 512 + h0 + 4 * tx);
  float* dst = ws + (which ? OFF_B : OFF_A) + (size_t)r * PLANE;
#pragma unroll
  for (int c = 0; c < 4; ++c) {
    float4 v;
    v.x = acc[c * 4 + 0] + bb.x;
    v.y = acc[c * 4 + 1] + bb.y;
    v.z = acc[c * 4 + 2] + bb.z;
    v.w = acc[c * 4 + 3] + bb.w;
    *(float4*)(dst + (size_t)(i0 + 4 * ty + c) * 512 + h0 + 4 * tx) = v;
  }
}

// ---------------- K1: row stats + gamma / (beta,w2) packing ----------------
// one wave per (which, r, row); grid 1024 x 256
__global__ __launch_bounds__(256) void k1_stats(float* __restrict__ ws,
                                                const float* __restrict__ gamma,
                                                const float* __restrict__ beta,
                                                const float* __restrict__ w2) {
  const int t = threadIdx.x;
  const int gw = (blockIdx.x * 256 + t) >> 6;  // 0..4095
  const int lane = t & 63;
  const int which = gw >> 11;
  const int rr = (gw >> 9) & 3;
  const int row = gw & 511;
  const float* src =
      ws + (which ? OFF_B : OFF_A) + (size_t)(rr * 512 + row) * 512 + lane * 8;
  float s = 0.f, q = 0.f;
#pragma unroll
  for (int c = 0; c < 2; ++c) {
    const float4 v = *(const float4*)(src + c * 4);
    s += v.x + v.y + v.z + v.w;
    q += v.x * v.x + v.y * v.y + v.z * v.z + v.w * v.w;
  }
#pragma unroll
  for (int off = 32; off >= 1; off >>= 1) {
    s += __shfl_down(s, off, 64);
    q += __shfl_down(q, off, 64);
  }
  if (lane == 0) {
    ws[(which ? OFF_MB : OFF_MA) + rr * 512 + row] = s * (1.f / 512.f);
    ws[(which ? OFF_QB : OFF_QA) + rr * 512 + row] = q;
  }
  if (blockIdx.x < 8) {
    const int idx = blockIdx.x * 256 + t;  // 0..2047 == r*512+k
    ws[OFF_G + idx] = gamma[idx];
    float2 bw;
    bw.x = beta[idx];
    bw.y = w2[idx];
    *(float2*)(ws + OFF_BW + (size_t)idx * 2) = bw;
  }
}

// ---------------- K2: pairwise dot  dotp[ks][r][i][j] = sum_k a.b' ----------------
// grid 512 = 8jt x 8it x 4r x 2ks; block 256 (16x16, 4x4 reg tile)
// pk version: pair accumulators over c (a4.xy / a4.zw are natural VGPR pairs);
// per k: 8 v_pk_fma_f32 + 4 b-splat movs, vs 16 v_fma_f32.
__global__ __launch_bounds__(256) void k2_dot(float* __restrict__ ws) {
  const int b = blockIdx.x;
  const int jt = b & 7, it = (b >> 3) & 7, r = (b >> 6) & 3, ks = b >> 8;
  const int i0 = it << 6, j0 = jt << 6;
  const int kb = ks << 8;
  const int t = threadIdx.x;
  const int tx = t & 15, ty = t >> 4;

  __shared__ float As[16 * 68];
  __shared__ float Bs[16 * 68];

  // acc2[cp][d] = {acc[(2cp)*4+d], acc[(2cp+1)*4+d]}
  v2f acc2[2][4];
#pragma unroll
  for (int cp = 0; cp < 2; ++cp)
#pragma unroll
    for (int d = 0; d < 4; ++d) { acc2[cp][d].x = 0.f; acc2[cp][d].y = 0.f; }

  const int srow = t >> 2, sf4 = (t & 3) << 2;
  const float* arow = ws + OFF_A + (size_t)(r * 512 + i0 + srow) * 512 + kb;
  const float* brow = ws + OFF_B + (size_t)(r * 512 + j0 + srow) * 512 + kb;

  for (int k0 = 0; k0 < 256; k0 += 16) {
    const float4 av = *(const float4*)(arow + k0 + sf4);
    const float4 bv = *(const float4*)(brow + k0 + sf4);
    __syncthreads();
    As[(sf4 + 0) * 68 + srow] = av.x;
    As[(sf4 + 1) * 68 + srow] = av.y;
    As[(sf4 + 2) * 68 + srow] = av.z;
    As[(sf4 + 3) * 68 + srow] = av.w;
    Bs[(sf4 + 0) * 68 + srow] = bv.x;
    Bs[(sf4 + 1) * 68 + srow] = bv.y;
    Bs[(sf4 + 2) * 68 + srow] = bv.z;
    Bs[(sf4 + 3) * 68 + srow] = bv.w;
    __syncthreads();
#pragma unroll
    for (int k = 0; k < 16; ++k) {
      const float4 a4 = *(const float4*)&As[k * 68 + 4 * ty];
      const float4 b4 = *(const float4*)&Bs[k * 68 + 4 * tx];
      v2f alo; alo.x = a4.x; alo.y = a4.y;
      v2f ahi; ahi.x = a4.z; ahi.y = a4.w;
      const float bvv[4] = {b4.x, b4.y, b4.z, b4.w};
#pragma unroll
      for (int d = 0; d < 4; ++d) {
        v2f bs; bs.x = bvv[d]; bs.y = bvv[d];
        pk_fma_acc(acc2[0][d], alo, bs);
        pk_fma_acc(acc2[1][d], ahi, bs);
      }
    }
  }
  float* dst = ws + OFF_DOT + (size_t)ks * (4 * PLANE) + (size_t)r * PLANE;
#pragma unroll
  for (int c = 0; c < 4; ++c) {
    float4 v;
    v.x = (c & 1) ? acc2[c >> 1][0].y : acc2[c >> 1][0].x;
    v.y = (c & 1) ? acc2[c >> 1][1].y : acc2[c >> 1][1].x;
    v.z = (c & 1) ? acc2[c >> 1][2].y : acc2[c >> 1][2].x;
    v.w = (c & 1) ? acc2[c >> 1][3].y : acc2[c >> 1][3].x;
    *(float4*)(dst + (size_t)(i0 + 4 * ty + c) * 512 + j0 + 4 * tx) = v;
  }
}

// ---------------- K3: score kernel v4 (packed fp32 inner) ----------------
// grid 512 = 8jt x 8it x 4r x 2ks; block 256 (16tx x 16ty; 4i x 4j reg tile).
// Same staging/swizzle/prefetch as v3. Inner loop pairs tuples over j:
// per (c, j-pair): v_pk_add (u), v_pk_fma (*Sv+beta), 2x v_max (relu),
// v_pk_fma (acc += m*w2) -> 5 instr + splats per 2 tuples, vs 8 scalar.
__global__ __launch_bounds__(256) void k3_score(float* __restrict__ ws) {
  const int b = blockIdx.x;
  const int jt = b & 7, it = (b >> 3) & 7, r = (b >> 6) & 3, ks = b >> 8;
  const int i0 = it << 6, j0 = jt << 6;
  const int t = threadIdx.x;
  const int tx = t & 15, ty = t >> 4;

  __shared__ float As2[64 * 68];  // [k][row-swizzled], pitch 68 (16B-aligned rows)
  __shared__ float Bs2[64 * 68];
  __shared__ float bwS[64 * 2];   // (beta, w2) per k of current chunk

  // ---- per-pair LN inverse-sigma Sv2[8] (paired over j); shift via centering ----
  const float4 mav = *(const float4*)(ws + OFF_MA + r * 512 + i0 + 4 * ty);
  const float4 qav = *(const float4*)(ws + OFF_QA + r * 512 + i0 + 4 * ty);
  const float4 mbv = *(const float4*)(ws + OFF_MB + r * 512 + j0 + 4 * tx);
  const float4 qbv = *(const float4*)(ws + OFF_QB + r * 512 + j0 + 4 * tx);
  const float mavA[4] = {mav.x, mav.y, mav.z, mav.w};
  const float qavA[4] = {qav.x, qav.y, qav.z, qav.w};
  const float mbA[4] = {mbv.x, mbv.y, mbv.z, mbv.w};
  const float qbA[4] = {qbv.x, qbv.y, qbv.z, qbv.w};
  v2f Sv2[8], acc2[8];
#pragma unroll
  for (int c = 0; c < 4; ++c) {
    const size_t doff = (size_t)r * PLANE + (size_t)(i0 + 4 * ty + c) * 512 + j0 + 4 * tx;
    const float4 d0 = *(const float4*)(ws + OFF_DOT + doff);
    const float4 d1 = *(const float4*)(ws + OFF_DOT + 4 * PLANE + doff);
    const float dA[4] = {d0.x + d1.x, d0.y + d1.y, d0.z + d1.z, d0.w + d1.w};
#pragma unroll
    for (int d = 0; d < 4; ++d) {
      const float mu = mavA[c] + mbA[d];
      const float msq = (qavA[c] + qbA[d] + 2.f * dA[d]) * (1.f / 512.f);
      const float var = msq - mu * mu;
      const float sv = 1.0f / sqrtf(var + 1e-5f);   // precise (no fast-math)
      Sv2[c * 2 + (d >> 1)][d & 1] = sv;
      acc2[c * 2 + (d >> 1)][d & 1] = 0.f;
    }
  }

  // ---- staging geometry: thread loads 4 rows (srow+16*c2) x 4 k (sf4..+3) ----
  const int kbase = ks << 8;
  const int srow = ty;              // 0..15
  const int sf4 = tx << 2;          // 0..60; (k>>2)&7 == tx&7 for all 4 staged k
  const int sblk = tx & 7;
  // centering means for the staged rows (scalar, L2-hot)
  float maR[4], mbR[4];
#pragma unroll
  for (int c2 = 0; c2 < 4; ++c2) {
    maR[c2] = ws[OFF_MA + r * 512 + i0 + srow + 16 * c2];
    mbR[c2] = ws[OFF_MB + r * 512 + j0 + srow + 16 * c2];
  }

  float4 aC[4], bC[4], gC;
  float2 bwC = make_float2(0.f, 0.f);
  {
    const int kb = kbase;
    gC = *(const float4*)(ws + OFF_G + r * 512 + kb + sf4);
#pragma unroll
    for (int c2 = 0; c2 < 4; ++c2) {
      aC[c2] = *(const float4*)(ws + OFF_A + (size_t)(r * 512 + i0 + srow + 16 * c2) * 512 + kb + sf4);
      bC[c2] = *(const float4*)(ws + OFF_B + (size_t)(r * 512 + j0 + srow + 16 * c2) * 512 + kb + sf4);
    }
    if (t < 64) bwC = *(const float2*)(ws + OFF_BW + (size_t)(r * 512 + kb + t) * 2);
  }

#pragma unroll
  for (int kc = 0; kc < 4; ++kc) {
    __syncthreads();  // previous chunk's LDS reads complete before overwrite
    // ---- stage current chunk (centered + gamma-scaled), swizzled stores ----
    {
      const float ga[4] = {gC.x, gC.y, gC.z, gC.w};
#pragma unroll
      for (int c2 = 0; c2 < 4; ++c2) {
        const int row = srow + 16 * c2;
        const int off = (((row >> 2) ^ sblk) << 2) + (row & 3);
        const float aq[4] = {aC[c2].x, aC[c2].y, aC[c2].z, aC[c2].w};
        const float bq[4] = {bC[c2].x, bC[c2].y, bC[c2].z, bC[c2].w};
#pragma unroll
        for (int q = 0; q < 4; ++q) {
          As2[(sf4 + q) * 68 + off] = (aq[q] - maR[c2]) * ga[q];
          Bs2[(sf4 + q) * 68 + off] = (bq[q] - mbR[c2]) * ga[q];
        }
      }
      if (t < 64) *(float2*)(bwS + 2 * t) = bwC;
    }
    // ---- prefetch next chunk's globals (overlap with compute below) ----
    if (kc < 3) {
      const int kb = kbase + ((kc + 1) << 6);
      gC = *(const float4*)(ws + OFF_G + r * 512 + kb + sf4);
#pragma unroll
      for (int c2 = 0; c2 < 4; ++c2) {
        aC[c2] = *(const float4*)(ws + OFF_A + (size_t)(r * 512 + i0 + srow + 16 * c2) * 512 + kb + sf4);
        bC[c2] = *(const float4*)(ws + OFF_B + (size_t)(r * 512 + j0 + srow + 16 * c2) * 512 + kb + sf4);
      }
      if (t < 64) bwC = *(const float2*)(ws + OFF_BW + (size_t)(r * 512 + kb + t) * 2);
    }
    __syncthreads();  // staged data visible

    v2f cacc2[8];
#pragma unroll
    for (int p = 0; p < 8; ++p) { cacc2[p].x = 0.f; cacc2[p].y = 0.f; }

#pragma unroll 4
    for (int k = 0; k < 64; ++k) {
      const int K = (k >> 2) & 7;
      const float4 aA = *(const float4*)&As2[k * 68 + ((ty ^ K) << 2)];  // b128, 4 uniq addrs
      const float4 bB = *(const float4*)&Bs2[k * 68 + ((tx ^ K) << 2)];  // b128, 2-way free
      const float2 bw = *(const float2*)&bwS[2 * k];                     // b64 broadcast
      v2f blo; blo.x = bB.x; blo.y = bB.y;   // natural VGPR pair
      v2f bhi; bhi.x = bB.z; bhi.y = bB.w;
      v2f be;  be.x = bw.x;  be.y = bw.x;    // beta splat (1 mov)
      v2f w2v; w2v.x = bw.y; w2v.y = bw.y;   // w2 splat (1 mov)
      const float aq[4] = {aA.x, aA.y, aA.z, aA.w};
#pragma unroll
      for (int c = 0; c < 4; ++c) {
        v2f as; as.x = aq[c]; as.y = aq[c];  // a splat (1 mov)
#pragma unroll
        for (int h = 0; h < 2; ++h) {
          const int p = c * 2 + h;
          const v2f u = pk_add(as, h ? bhi : blo);       // (a-ma)g + (b-mb)g
          const v2f hn = pk_fma(u, Sv2[p], be);          // *Sv + beta
          v2f m;
          m.x = fmaxf(hn.x, 0.f);                        // relu (no pk_max_f32)
          m.y = fmaxf(hn.y, 0.f);
          pk_fma_acc(cacc2[p], m, w2v);                  // acc += m*w2
        }
      }
    }
    // chunked accumulation: keeps summation error ~2e-7
#pragma unroll
    for (int p = 0; p < 8; ++p) {
      acc2[p].x += cacc2[p].x;
      acc2[p].y += cacc2[p].y;
    }
  }

  float* dst = ws + OFF_S + (size_t)ks * (4 * PLANE) + (size_t)r * PLANE;
#pragma unroll
  for (int c = 0; c < 4; ++c) {
    float4 v;
    v.x = acc2[c * 2 + 0].x;
    v.y = acc2[c * 2 + 0].y;
    v.z = acc2[c * 2 + 1].x;
    v.w = acc2[c * 2 + 1].y;
    *(float4*)(dst + (size_t)(i0 + 4 * ty + c) * 512 + j0 + 4 * tx) = v;
  }
}

// ---------------- K4: combine + outputs ----------------
__global__ __launch_bounds__(256) void k4_combine(const float* __restrict__ ws,
                                                  const float* __restrict__ img,
                                                  const float* __restrict__ txt,
                                                  const float* __restrict__ b2,
                                                  float* __restrict__ out) {
  const int idx = blockIdx.x * 256 + threadIdx.x;  // 0..262143
  const int i = idx >> 9, j = idx & 511;
  const float* s0 = ws + OFF_S;
  const float* s1 = ws + OFF_S + 4 * PLANE;
  float best = -3.4e38f;
  int rel = 0;
#pragma unroll
  for (int r = 0; r < 4; ++r) {
    const float s = s0[r * PLANE + idx] + s1[r * PLANE + idx] + b2[r];
    if (s > best) { best = s; rel = r; }  // strict > == first-index argmax
  }
  out[idx] = (i < 256) ? img[idx] : txt[idx - 131072];
  out[PLANE + idx] = best;
  out[2 * PLANE + idx] = (float)rel;
  // match numpy: float32 best promoted to double vs python-float 0.2
  out[3 * PLANE + idx] = (i != j && (double)best > 0.2) ? 1.0f : 0.0f;
}

extern "C" void kernel_launch(void* const* d_in, const int* in_sizes, int n_in,
                              void* d_out, int out_size, void* d_ws, size_t ws_size,
                              hipStream_t stream) {
  const float* img   = (const float*)d_in[0];
  const float* txt   = (const float*)d_in[1];
  const float* W1    = (const float*)d_in[2];
  const float* b1    = (const float*)d_in[3];
  const float* gamma = (const float*)d_in[4];
  const float* beta  = (const float*)d_in[5];
  const float* w2    = (const float*)d_in[6];
  const float* b2    = (const float*)d_in[7];
  float* ws  = (float*)d_ws;
  float* out = (float*)d_out;
  (void)in_sizes; (void)n_in; (void)out_size; (void)ws_size;

  hipLaunchKernelGGL(k0_gemm,    dim3(512),  dim3(256), 0, stream, img, txt, W1, b1, ws);
  hipLaunchKernelGGL(k1_stats,   dim3(1024), dim3(256), 0, stream, ws, gamma, beta, w2);
  hipLaunchKernelGGL(k2_dot,     dim3(512),  dim3(256), 0, stream, ws);
  hipLaunchKernelGGL(k3_score,   dim3(512),  dim3(256), 0, stream, ws);
  hipLaunchKernelGGL(k4_combine, dim3(1024), dim3(256), 0, stream, ws, img, txt, b2, out);
}

// Round 4
// 193.750 us; speedup vs baseline: 1.0778x; 1.0778x over previous
//
#include <hip/hip_runtime.h>
#include <math.h>

// DynamicRelationModeler: x=concat(img,txt) [512x512]; per r: a=x@Wl_r^T, b=x@Wr_r^T;
// h=a_i+b_j+b1_r; LN over H; s=relu(hn)@w2_r+b2_r; argmax/max over r; mask.
//
// Round-4: packed-fp32 experiment reverted (v_pk_* is half-rate on gfx950 ->
// net negative, r3 measured). K2 back to r2 scalar form. K3 keeps the r2
// inner structure but tiles 64x32 (grid 1024 = 4 blocks/CU = 16 waves/CU)
// to close the ~26us VALU-idle gap seen at 2 blocks/CU.
//
// ws layout (floats):
//   Aarr [4][512][512]  a_r[i][h]
//   Barr [4][512][512]  b'_r[j][h] (b1 folded in)
//   dotp [2][4][512][512]  k-split partial pairwise dots a_i . b'_j
//   Spart[2][4][512][512]  k-split partial relu-dot scores
//   ma/qa/mb/qb [4][512]   row mean (a), row sum-of-squares, same for b'
//   G    [4][512]          gamma per (r,k)
//   BW   [4][512][2]       packed (beta, w2) per (r,k)

namespace {
constexpr size_t PLANE  = 512 * 512;            // 262144
constexpr size_t OFF_A   = 0;
constexpr size_t OFF_B   = OFF_A + 4 * PLANE;   // 1048576
constexpr size_t OFF_DOT = OFF_B + 4 * PLANE;   // 2097152
constexpr size_t OFF_S   = OFF_DOT + 8 * PLANE; // 4194304
constexpr size_t OFF_MA  = OFF_S + 8 * PLANE;   // 6291456
constexpr size_t OFF_QA  = OFF_MA + 2048;
constexpr size_t OFF_MB  = OFF_QA + 2048;
constexpr size_t OFF_QB  = OFF_MB + 2048;
constexpr size_t OFF_G   = OFF_QB + 2048;       // gamma [2048]
constexpr size_t OFF_BW  = OFF_G + 2048;        // (beta,w2) [2048][2]
}

// ---------------- K0: input GEMM  C[n][4096] = x @ [Wl|Wr]^T ----------------
// grid 512 = 8 i-tiles x 64 col-tiles; block 256 (16x16 threads, 4x4 reg tile)
__global__ __launch_bounds__(256) void k0_gemm(const float* __restrict__ img,
                                               const float* __restrict__ txt,
                                               const float* __restrict__ W1,
                                               const float* __restrict__ b1,
                                               float* __restrict__ ws) {
  const int b = blockIdx.x;
  const int it = b >> 6;
  const int ct = b & 63;
  const int which = ct >> 5;      // 0 -> a (Wl), 1 -> b (Wr)
  const int r = (ct >> 3) & 3;
  const int ht = ct & 7;
  const int i0 = it << 6, h0 = ht << 6;
  const int t = threadIdx.x;
  const int tx = t & 15, ty = t >> 4;

  __shared__ float Xs[16 * 68];   // [k][i], pitch 68 -> 16B-aligned rows for b128 reads
  __shared__ float Wsm[16 * 68];  // [k][h]

  float acc[16], pacc[16];
#pragma unroll
  for (int p = 0; p < 16; ++p) { acc[p] = 0.f; pacc[p] = 0.f; }

  const int srow = t >> 2;
  const int sf4 = (t & 3) << 2;
  const int xi = i0 + srow;
  const float* xrow = (xi < 256) ? (img + (size_t)xi * 512)
                                 : (txt + (size_t)(xi - 256) * 512);
  const float* wrow = W1 + (size_t)(r * 512 + h0 + srow) * 1024 + which * 512;

  for (int k0 = 0; k0 < 512; k0 += 16) {
    const float4 xv = *(const float4*)(xrow + k0 + sf4);
    const float4 wv = *(const float4*)(wrow + k0 + sf4);
    __syncthreads();
    Xs[(sf4 + 0) * 68 + srow] = xv.x;
    Xs[(sf4 + 1) * 68 + srow] = xv.y;
    Xs[(sf4 + 2) * 68 + srow] = xv.z;
    Xs[(sf4 + 3) * 68 + srow] = xv.w;
    Wsm[(sf4 + 0) * 68 + srow] = wv.x;
    Wsm[(sf4 + 1) * 68 + srow] = wv.y;
    Wsm[(sf4 + 2) * 68 + srow] = wv.z;
    Wsm[(sf4 + 3) * 68 + srow] = wv.w;
    __syncthreads();
#pragma unroll
    for (int k = 0; k < 16; ++k) {
      const float4 a4 = *(const float4*)&Xs[k * 68 + 4 * ty];
      const float4 b4 = *(const float4*)&Wsm[k * 68 + 4 * tx];
      const float av[4] = {a4.x, a4.y, a4.z, a4.w};
      const float bv[4] = {b4.x, b4.y, b4.z, b4.w};
#pragma unroll
      for (int c = 0; c < 4; ++c)
#pragma unroll
        for (int d = 0; d < 4; ++d)
          pacc[c * 4 + d] = fmaf(av[c], bv[d], pacc[c * 4 + d]);
    }
    // fold per-stage partial into master (split accumulation: ~1e-7 error)
#pragma unroll
    for (int p = 0; p < 16; ++p) { acc[p] += pacc[p]; pacc[p] = 0.f; }
  }

  float4 bb = make_float4(0.f, 0.f, 0.f, 0.f);
  if (which) bb = *(const float4*)(b1 + r * 512 + h0 + 4 * tx);
  float* dst = ws + (which ? OFF_B : OFF_A) + (size_t)r * PLANE;
#pragma unroll
  for (int c = 0; c < 4; ++c) {
    float4 v;
    v.x = acc[c * 4 + 0] + bb.x;
    v.y = acc[c * 4 + 1] + bb.y;
    v.z = acc[c * 4 + 2] + bb.z;
    v.w = acc[c * 4 + 3] + bb.w;
    *(float4*)(dst + (size_t)(i0 + 4 * ty + c) * 512 + h0 + 4 * tx) = v;
  }
}

// ---------------- K1: row stats + gamma / (beta,w2) packing ----------------
// one wave per (which, r, row); grid 1024 x 256
__global__ __launch_bounds__(256) void k1_stats(float* __restrict__ ws,
                                                const float* __restrict__ gamma,
                                                const float* __restrict__ beta,
                                                const float* __restrict__ w2) {
  const int t = threadIdx.x;
  const int gw = (blockIdx.x * 256 + t) >> 6;  // 0..4095
  const int lane = t & 63;
  const int which = gw >> 11;
  const int rr = (gw >> 9) & 3;
  const int row = gw & 511;
  const float* src =
      ws + (which ? OFF_B : OFF_A) + (size_t)(rr * 512 + row) * 512 + lane * 8;
  float s = 0.f, q = 0.f;
#pragma unroll
  for (int c = 0; c < 2; ++c) {
    const float4 v = *(const float4*)(src + c * 4);
    s += v.x + v.y + v.z + v.w;
    q += v.x * v.x + v.y * v.y + v.z * v.z + v.w * v.w;
  }
#pragma unroll
  for (int off = 32; off >= 1; off >>= 1) {
    s += __shfl_down(s, off, 64);
    q += __shfl_down(q, off, 64);
  }
  if (lane == 0) {
    ws[(which ? OFF_MB : OFF_MA) + rr * 512 + row] = s * (1.f / 512.f);
    ws[(which ? OFF_QB : OFF_QA) + rr * 512 + row] = q;
  }
  if (blockIdx.x < 8) {
    const int idx = blockIdx.x * 256 + t;  // 0..2047 == r*512+k
    ws[OFF_G + idx] = gamma[idx];
    float2 bw;
    bw.x = beta[idx];
    bw.y = w2[idx];
    *(float2*)(ws + OFF_BW + (size_t)idx * 2) = bw;
  }
}

// ---------------- K2: pairwise dot  dotp[ks][r][i][j] = sum_k a.b' ----------------
// grid 512 = 8jt x 8it x 4r x 2ks; block 256 (16x16, 4x4 reg tile)
// (r2 scalar form restored: v_pk_fma_f32 measured half-rate on gfx950, r3)
__global__ __launch_bounds__(256) void k2_dot(float* __restrict__ ws) {
  const int b = blockIdx.x;
  const int jt = b & 7, it = (b >> 3) & 7, r = (b >> 6) & 3, ks = b >> 8;
  const int i0 = it << 6, j0 = jt << 6;
  const int kb = ks << 8;
  const int t = threadIdx.x;
  const int tx = t & 15, ty = t >> 4;

  __shared__ float As[16 * 68];
  __shared__ float Bs[16 * 68];

  float acc[16];
#pragma unroll
  for (int p = 0; p < 16; ++p) acc[p] = 0.f;

  const int srow = t >> 2, sf4 = (t & 3) << 2;
  const float* arow = ws + OFF_A + (size_t)(r * 512 + i0 + srow) * 512 + kb;
  const float* brow = ws + OFF_B + (size_t)(r * 512 + j0 + srow) * 512 + kb;

  for (int k0 = 0; k0 < 256; k0 += 16) {
    const float4 av = *(const float4*)(arow + k0 + sf4);
    const float4 bv = *(const float4*)(brow + k0 + sf4);
    __syncthreads();
    As[(sf4 + 0) * 68 + srow] = av.x;
    As[(sf4 + 1) * 68 + srow] = av.y;
    As[(sf4 + 2) * 68 + srow] = av.z;
    As[(sf4 + 3) * 68 + srow] = av.w;
    Bs[(sf4 + 0) * 68 + srow] = bv.x;
    Bs[(sf4 + 1) * 68 + srow] = bv.y;
    Bs[(sf4 + 2) * 68 + srow] = bv.z;
    Bs[(sf4 + 3) * 68 + srow] = bv.w;
    __syncthreads();
#pragma unroll
    for (int k = 0; k < 16; ++k) {
      const float4 a4 = *(const float4*)&As[k * 68 + 4 * ty];
      const float4 b4 = *(const float4*)&Bs[k * 68 + 4 * tx];
      const float av2[4] = {a4.x, a4.y, a4.z, a4.w};
      const float bv2[4] = {b4.x, b4.y, b4.z, b4.w};
#pragma unroll
      for (int c = 0; c < 4; ++c)
#pragma unroll
        for (int d = 0; d < 4; ++d)
          acc[c * 4 + d] = fmaf(av2[c], bv2[d], acc[c * 4 + d]);
    }
  }
  float* dst = ws + OFF_DOT + (size_t)ks * (4 * PLANE) + (size_t)r * PLANE;
#pragma unroll
  for (int c = 0; c < 4; ++c) {
    float4 v;
    v.x = acc[c * 4 + 0]; v.y = acc[c * 4 + 1];
    v.z = acc[c * 4 + 2]; v.w = acc[c * 4 + 3];
    *(float4*)(dst + (size_t)(i0 + 4 * ty + c) * 512 + j0 + 4 * tx) = v;
  }
}

// ---------------- K3: score kernel v5 (64x32 tile, 4 blocks/CU) ----------------
// grid 1024 = 16jt x 8it x 4r x 2ks; block 256 (16tx x 16ty; 4i x 2j reg tile).
// Same centered-LN 4-op inner chain and XOR-swizzled [k][row] LDS as r2;
// tile halved along j so 4 blocks/CU are resident (16 waves/CU, was 8) to
// close the VALU-idle gap (r2: VALUBusy 65% at Occupancy 18%).
__global__ __launch_bounds__(256) void k3_score(float* __restrict__ ws) {
  const int b = blockIdx.x;
  const int jt = b & 15, it = (b >> 4) & 7, r = (b >> 7) & 3, ks = b >> 9;
  const int i0 = it << 6, j0 = jt << 5;
  const int t = threadIdx.x;
  const int tx = t & 15, ty = t >> 4;

  __shared__ float As2[64 * 68];  // [k][i-row swizzled], 64 rows, pitch 68
  __shared__ float Bs2[64 * 36];  // [k][j-row swizzled], 32 rows, pitch 36
  __shared__ float bwS[64 * 2];   // (beta, w2) per k of current chunk

  // ---- per-pair LN inverse-sigma Sv[8] (4i x 2j); shift via centering ----
  const float4 mav = *(const float4*)(ws + OFF_MA + r * 512 + i0 + 4 * ty);
  const float4 qav = *(const float4*)(ws + OFF_QA + r * 512 + i0 + 4 * ty);
  const float2 mbv = *(const float2*)(ws + OFF_MB + r * 512 + j0 + 2 * tx);
  const float2 qbv = *(const float2*)(ws + OFF_QB + r * 512 + j0 + 2 * tx);
  const float mavA[4] = {mav.x, mav.y, mav.z, mav.w};
  const float qavA[4] = {qav.x, qav.y, qav.z, qav.w};
  const float mbA[2] = {mbv.x, mbv.y};
  const float qbA[2] = {qbv.x, qbv.y};
  float Sv[8], acc[8];
#pragma unroll
  for (int c = 0; c < 4; ++c) {
    const size_t doff = (size_t)r * PLANE + (size_t)(i0 + 4 * ty + c) * 512 + j0 + 2 * tx;
    const float2 d0 = *(const float2*)(ws + OFF_DOT + doff);
    const float2 d1 = *(const float2*)(ws + OFF_DOT + 4 * PLANE + doff);
    const float dA[2] = {d0.x + d1.x, d0.y + d1.y};
#pragma unroll
    for (int d = 0; d < 2; ++d) {
      const int p = c * 2 + d;
      const float mu = mavA[c] + mbA[d];
      const float msq = (qavA[c] + qbA[d] + 2.f * dA[d]) * (1.f / 512.f);
      const float var = msq - mu * mu;
      Sv[p] = 1.0f / sqrtf(var + 1e-5f);   // precise (no fast-math)
      acc[p] = 0.f;
    }
  }

  // ---- staging geometry: thread covers k sf4..sf4+3; A rows ty+16*{0..3},
  //      B rows ty+16*{0,1}. Swizzle: row-group ^= (k>>2)&7 at 16B grain. ----
  const int kbase = ks << 8;
  const int srow = ty;              // 0..15
  const int sf4 = tx << 2;          // 0..60; (k>>2)&7 == tx&7 for staged k
  const int sblk = tx & 7;
  float maR[4], mbR[2];
#pragma unroll
  for (int c2 = 0; c2 < 4; ++c2)
    maR[c2] = ws[OFF_MA + r * 512 + i0 + srow + 16 * c2];
#pragma unroll
  for (int c2 = 0; c2 < 2; ++c2)
    mbR[c2] = ws[OFF_MB + r * 512 + j0 + srow + 16 * c2];

  float4 aC[4], bC[2], gC;
  float2 bwC = make_float2(0.f, 0.f);
  {
    const int kb = kbase;
    gC = *(const float4*)(ws + OFF_G + r * 512 + kb + sf4);
#pragma unroll
    for (int c2 = 0; c2 < 4; ++c2)
      aC[c2] = *(const float4*)(ws + OFF_A + (size_t)(r * 512 + i0 + srow + 16 * c2) * 512 + kb + sf4);
#pragma unroll
    for (int c2 = 0; c2 < 2; ++c2)
      bC[c2] = *(const float4*)(ws + OFF_B + (size_t)(r * 512 + j0 + srow + 16 * c2) * 512 + kb + sf4);
    if (t < 64) bwC = *(const float2*)(ws + OFF_BW + (size_t)(r * 512 + kb + t) * 2);
  }

#pragma unroll
  for (int kc = 0; kc < 4; ++kc) {
    __syncthreads();  // previous chunk's LDS reads complete before overwrite
    // ---- stage current chunk (centered + gamma-scaled), swizzled stores ----
    {
      const float ga[4] = {gC.x, gC.y, gC.z, gC.w};
#pragma unroll
      for (int c2 = 0; c2 < 4; ++c2) {
        const int row = srow + 16 * c2;
        const int off = (((row >> 2) ^ sblk) << 2) + (row & 3);
        const float aq[4] = {aC[c2].x, aC[c2].y, aC[c2].z, aC[c2].w};
#pragma unroll
        for (int q = 0; q < 4; ++q)
          As2[(sf4 + q) * 68 + off] = (aq[q] - maR[c2]) * ga[q];
      }
#pragma unroll
      for (int c2 = 0; c2 < 2; ++c2) {
        const int row = srow + 16 * c2;
        const int off = (((row >> 2) ^ sblk) << 2) + (row & 3);
        const float bq[4] = {bC[c2].x, bC[c2].y, bC[c2].z, bC[c2].w};
#pragma unroll
        for (int q = 0; q < 4; ++q)
          Bs2[(sf4 + q) * 36 + off] = (bq[q] - mbR[c2]) * ga[q];
      }
      if (t < 64) *(float2*)(bwS + 2 * t) = bwC;
    }
    // ---- prefetch next chunk's globals (overlap with compute below) ----
    if (kc < 3) {
      const int kb = kbase + ((kc + 1) << 6);
      gC = *(const float4*)(ws + OFF_G + r * 512 + kb + sf4);
#pragma unroll
      for (int c2 = 0; c2 < 4; ++c2)
        aC[c2] = *(const float4*)(ws + OFF_A + (size_t)(r * 512 + i0 + srow + 16 * c2) * 512 + kb + sf4);
#pragma unroll
      for (int c2 = 0; c2 < 2; ++c2)
        bC[c2] = *(const float4*)(ws + OFF_B + (size_t)(r * 512 + j0 + srow + 16 * c2) * 512 + kb + sf4);
      if (t < 64) bwC = *(const float2*)(ws + OFF_BW + (size_t)(r * 512 + kb + t) * 2);
    }
    __syncthreads();  // staged data visible

    float cacc[8];
#pragma unroll
    for (int p = 0; p < 8; ++p) cacc[p] = 0.f;

#pragma unroll 4
    for (int k = 0; k < 64; ++k) {
      const int K = (k >> 2) & 7;
      const float4 aA = *(const float4*)&As2[k * 68 + ((ty ^ K) << 2)];  // b128
      const float2 bB = *(const float2*)&Bs2[k * 36 + (((tx >> 1) ^ K) << 2) + ((tx & 1) << 1)];  // b64
      const float2 bw = *(const float2*)&bwS[2 * k];                     // b64 broadcast
      const float aq[4] = {aA.x, aA.y, aA.z, aA.w};
      const float bq[2] = {bB.x, bB.y};
#pragma unroll
      for (int c = 0; c < 4; ++c)
#pragma unroll
        for (int d = 0; d < 2; ++d) {
          const int p = c * 2 + d;
          const float u = aq[c] + bq[d];              // (a-ma)g + (b-mb)g
          const float hn = fmaf(u, Sv[p], bw.x);      // *Sv + beta
          const float m = fmaxf(hn, 0.f);             // relu
          cacc[p] = fmaf(m, bw.y, cacc[p]);           // *w2, accumulate
        }
    }
    // chunked accumulation: keeps summation error ~2e-7
#pragma unroll
    for (int p = 0; p < 8; ++p) acc[p] += cacc[p];
  }

  float* dst = ws + OFF_S + (size_t)ks * (4 * PLANE) + (size_t)r * PLANE;
#pragma unroll
  for (int c = 0; c < 4; ++c) {
    float2 v;
    v.x = acc[c * 2 + 0];
    v.y = acc[c * 2 + 1];
    *(float2*)(dst + (size_t)(i0 + 4 * ty + c) * 512 + j0 + 2 * tx) = v;
  }
}

// ---------------- K4: combine + outputs ----------------
__global__ __launch_bounds__(256) void k4_combine(const float* __restrict__ ws,
                                                  const float* __restrict__ img,
                                                  const float* __restrict__ txt,
                                                  const float* __restrict__ b2,
                                                  float* __restrict__ out) {
  const int idx = blockIdx.x * 256 + threadIdx.x;  // 0..262143
  const int i = idx >> 9, j = idx & 511;
  const float* s0 = ws + OFF_S;
  const float* s1 = ws + OFF_S + 4 * PLANE;
  float best = -3.4e38f;
  int rel = 0;
#pragma unroll
  for (int r = 0; r < 4; ++r) {
    const float s = s0[r * PLANE + idx] + s1[r * PLANE + idx] + b2[r];
    if (s > best) { best = s; rel = r; }  // strict > == first-index argmax
  }
  out[idx] = (i < 256) ? img[idx] : txt[idx - 131072];
  out[PLANE + idx] = best;
  out[2 * PLANE + idx] = (float)rel;
  // match numpy: float32 best promoted to double vs python-float 0.2
  out[3 * PLANE + idx] = (i != j && (double)best > 0.2) ? 1.0f : 0.0f;
}

extern "C" void kernel_launch(void* const* d_in, const int* in_sizes, int n_in,
                              void* d_out, int out_size, void* d_ws, size_t ws_size,
                              hipStream_t stream) {
  const float* img   = (const float*)d_in[0];
  const float* txt   = (const float*)d_in[1];
  const float* W1    = (const float*)d_in[2];
  const float* b1    = (const float*)d_in[3];
  const float* gamma = (const float*)d_in[4];
  const float* beta  = (const float*)d_in[5];
  const float* w2    = (const float*)d_in[6];
  const float* b2    = (const float*)d_in[7];
  float* ws  = (float*)d_ws;
  float* out = (float*)d_out;
  (void)in_sizes; (void)n_in; (void)out_size; (void)ws_size;

  hipLaunchKernelGGL(k0_gemm,    dim3(512),  dim3(256), 0, stream, img, txt, W1, b1, ws);
  hipLaunchKernelGGL(k1_stats,   dim3(1024), dim3(256), 0, stream, ws, gamma, beta, w2);
  hipLaunchKernelGGL(k2_dot,     dim3(512),  dim3(256), 0, stream, ws);
  hipLaunchKernelGGL(k3_score,   dim3(1024), dim3(256), 0, stream, ws);
  hipLaunchKernelGGL(k4_combine, dim3(1024), dim3(256), 0, stream, ws, img, txt, b2, out);
}

// Round 5
// 191.892 us; speedup vs baseline: 1.0883x; 1.0097x over previous
//
#include <hip/hip_runtime.h>
#include <math.h>

// DynamicRelationModeler: x=concat(img,txt) [512x512]; per r: a=x@Wl_r^T, b=x@Wr_r^T;
// h=a_i+b_j+b1_r; LN over H; s=relu(hn)@w2_r+b2_r; argmax/max over r; mask.
//
// Round-5: K3 uses relu(x) = 0.5(x+|x|). The linear half of the relu-dot is
// separable (Sv*(SA_i+SB_j)+Cb, precomputed per-row in K1); only the |hn|
// half needs per-tuple work, and |.| is a free VOP3 input modifier:
//   u = a+b; hn = fma(u,Sv,beta); acc = fma(c,|hn|,acc)   -> 3 ops/tuple (was 4).
//
// ws layout (floats):
//   Aarr [4][512][512]  a_r[i][h]
//   Barr [4][512][512]  b'_r[j][h] (b1 folded in)
//   dotp [2][4][512][512]  k-split partial pairwise dots a_i . b'_j
//   Spart[2][4][512][512]  k-split partial scores
//   ma/qa/mb/qb [4][512]   row mean, row sum-of-squares for a and b'
//   G    [4][512]          gamma per (r,k)
//   BW   [4][512][2]       packed (beta, w2/2) per (r,k)
//   SA/SB [4][512]         SA_i = sum_k (w2/2)*gamma*(a-ma),  SB_j likewise
//   CB   [4]               sum_k (w2/2)*beta

namespace {
constexpr size_t PLANE  = 512 * 512;            // 262144
constexpr size_t OFF_A   = 0;
constexpr size_t OFF_B   = OFF_A + 4 * PLANE;   // 1048576
constexpr size_t OFF_DOT = OFF_B + 4 * PLANE;   // 2097152
constexpr size_t OFF_S   = OFF_DOT + 8 * PLANE; // 4194304
constexpr size_t OFF_MA  = OFF_S + 8 * PLANE;   // 6291456
constexpr size_t OFF_QA  = OFF_MA + 2048;
constexpr size_t OFF_MB  = OFF_QA + 2048;
constexpr size_t OFF_QB  = OFF_MB + 2048;
constexpr size_t OFF_G   = OFF_QB + 2048;       // gamma [2048]
constexpr size_t OFF_BW  = OFF_G + 2048;        // (beta, w2/2) [2048][2]
constexpr size_t OFF_SA  = OFF_BW + 4096;       // [2048]
constexpr size_t OFF_SB  = OFF_SA + 2048;       // [2048]
constexpr size_t OFF_CB  = OFF_SB + 2048;       // [4]
}

// ---------------- K0: input GEMM  C[n][4096] = x @ [Wl|Wr]^T ----------------
// grid 512 = 8 i-tiles x 64 col-tiles; block 256 (16x16 threads, 4x4 reg tile)
__global__ __launch_bounds__(256) void k0_gemm(const float* __restrict__ img,
                                               const float* __restrict__ txt,
                                               const float* __restrict__ W1,
                                               const float* __restrict__ b1,
                                               float* __restrict__ ws) {
  const int b = blockIdx.x;
  const int it = b >> 6;
  const int ct = b & 63;
  const int which = ct >> 5;      // 0 -> a (Wl), 1 -> b (Wr)
  const int r = (ct >> 3) & 3;
  const int ht = ct & 7;
  const int i0 = it << 6, h0 = ht << 6;
  const int t = threadIdx.x;
  const int tx = t & 15, ty = t >> 4;

  __shared__ float Xs[16 * 68];   // [k][i], pitch 68 -> 16B-aligned rows for b128 reads
  __shared__ float Wsm[16 * 68];  // [k][h]

  float acc[16], pacc[16];
#pragma unroll
  for (int p = 0; p < 16; ++p) { acc[p] = 0.f; pacc[p] = 0.f; }

  const int srow = t >> 2;
  const int sf4 = (t & 3) << 2;
  const int xi = i0 + srow;
  const float* xrow = (xi < 256) ? (img + (size_t)xi * 512)
                                 : (txt + (size_t)(xi - 256) * 512);
  const float* wrow = W1 + (size_t)(r * 512 + h0 + srow) * 1024 + which * 512;

  for (int k0 = 0; k0 < 512; k0 += 16) {
    const float4 xv = *(const float4*)(xrow + k0 + sf4);
    const float4 wv = *(const float4*)(wrow + k0 + sf4);
    __syncthreads();
    Xs[(sf4 + 0) * 68 + srow] = xv.x;
    Xs[(sf4 + 1) * 68 + srow] = xv.y;
    Xs[(sf4 + 2) * 68 + srow] = xv.z;
    Xs[(sf4 + 3) * 68 + srow] = xv.w;
    Wsm[(sf4 + 0) * 68 + srow] = wv.x;
    Wsm[(sf4 + 1) * 68 + srow] = wv.y;
    Wsm[(sf4 + 2) * 68 + srow] = wv.z;
    Wsm[(sf4 + 3) * 68 + srow] = wv.w;
    __syncthreads();
#pragma unroll
    for (int k = 0; k < 16; ++k) {
      const float4 a4 = *(const float4*)&Xs[k * 68 + 4 * ty];
      const float4 b4 = *(const float4*)&Wsm[k * 68 + 4 * tx];
      const float av[4] = {a4.x, a4.y, a4.z, a4.w};
      const float bv[4] = {b4.x, b4.y, b4.z, b4.w};
#pragma unroll
      for (int c = 0; c < 4; ++c)
#pragma unroll
        for (int d = 0; d < 4; ++d)
          pacc[c * 4 + d] = fmaf(av[c], bv[d], pacc[c * 4 + d]);
    }
    // fold per-stage partial into master (split accumulation: ~1e-7 error)
#pragma unroll
    for (int p = 0; p < 16; ++p) { acc[p] += pacc[p]; pacc[p] = 0.f; }
  }

  float4 bb = make_float4(0.f, 0.f, 0.f, 0.f);
  if (which) bb = *(const float4*)(b1 + r * 512 + h0 + 4 * tx);
  float* dst = ws + (which ? OFF_B : OFF_A) + (size_t)r * PLANE;
#pragma unroll
  for (int c = 0; c < 4; ++c) {
    float4 v;
    v.x = acc[c * 4 + 0] + bb.x;
    v.y = acc[c * 4 + 1] + bb.y;
    v.z = acc[c * 4 + 2] + bb.z;
    v.w = acc[c * 4 + 3] + bb.w;
    *(float4*)(dst + (size_t)(i0 + 4 * ty + c) * 512 + h0 + 4 * tx) = v;
  }
}

// ---------------- K1: row stats + relu-linear row sums + packing ----------------
// one wave per (which, r, row); grid 1024 x 256.
// Per row also computes SA_i = sum_k cg*(a-ma) = sum_k cg*a - ma*sum_k cg,
// with cg = 0.5*w2*gamma (the separable half of relu).
__global__ __launch_bounds__(256) void k1_stats(float* __restrict__ ws,
                                                const float* __restrict__ gamma,
                                                const float* __restrict__ beta,
                                                const float* __restrict__ w2) {
  const int t = threadIdx.x;
  const int gw = (blockIdx.x * 256 + t) >> 6;  // 0..4095
  const int lane = t & 63;
  const int which = gw >> 11;
  const int rr = (gw >> 9) & 3;
  const int row = gw & 511;
  const float* src =
      ws + (which ? OFF_B : OFF_A) + (size_t)(rr * 512 + row) * 512 + lane * 8;
  const float* gsrc = gamma + rr * 512 + lane * 8;
  const float* wsrc = w2 + rr * 512 + lane * 8;
  float s = 0.f, q = 0.f, sa = 0.f, cgs = 0.f;
#pragma unroll
  for (int c = 0; c < 2; ++c) {
    const float4 v = *(const float4*)(src + c * 4);
    const float4 g = *(const float4*)(gsrc + c * 4);
    const float4 w = *(const float4*)(wsrc + c * 4);
    s += v.x + v.y + v.z + v.w;
    q += v.x * v.x + v.y * v.y + v.z * v.z + v.w * v.w;
    const float cgx = 0.5f * w.x * g.x;
    const float cgy = 0.5f * w.y * g.y;
    const float cgz = 0.5f * w.z * g.z;
    const float cgw = 0.5f * w.w * g.w;
    sa += cgx * v.x + cgy * v.y + cgz * v.z + cgw * v.w;
    cgs += cgx + cgy + cgz + cgw;
  }
#pragma unroll
  for (int off = 32; off >= 1; off >>= 1) {
    s += __shfl_down(s, off, 64);
    q += __shfl_down(q, off, 64);
    sa += __shfl_down(sa, off, 64);
    cgs += __shfl_down(cgs, off, 64);
  }
  if (lane == 0) {
    const float ma = s * (1.f / 512.f);
    ws[(which ? OFF_MB : OFF_MA) + rr * 512 + row] = ma;
    ws[(which ? OFF_QB : OFF_QA) + rr * 512 + row] = q;
    ws[(which ? OFF_SB : OFF_SA) + rr * 512 + row] = sa - ma * cgs;
  }
  if (blockIdx.x < 8) {
    const int idx = blockIdx.x * 256 + t;  // 0..2047 == r*512+k
    ws[OFF_G + idx] = gamma[idx];
    float2 bw;
    bw.x = beta[idx];
    bw.y = 0.5f * w2[idx];    // c = w2/2
    *(float2*)(ws + OFF_BW + (size_t)idx * 2) = bw;
  }
  if (blockIdx.x == 8) {
    const int rb = t >> 6;   // 0..3
    float cb = 0.f;
#pragma unroll
    for (int c = 0; c < 8; ++c)
      cb += 0.5f * w2[rb * 512 + lane * 8 + c] * beta[rb * 512 + lane * 8 + c];
#pragma unroll
    for (int off = 32; off >= 1; off >>= 1) cb += __shfl_down(cb, off, 64);
    if (lane == 0) ws[OFF_CB + rb] = cb;
  }
}

// ---------------- K2: pairwise dot  dotp[ks][r][i][j] = sum_k a.b' ----------------
// grid 512 = 8jt x 8it x 4r x 2ks; block 256 (16x16, 4x4 reg tile)
// (r2 scalar form: v_pk_fma_f32 measured half-rate on gfx950, r3)
__global__ __launch_bounds__(256) void k2_dot(float* __restrict__ ws) {
  const int b = blockIdx.x;
  const int jt = b & 7, it = (b >> 3) & 7, r = (b >> 6) & 3, ks = b >> 8;
  const int i0 = it << 6, j0 = jt << 6;
  const int kb = ks << 8;
  const int t = threadIdx.x;
  const int tx = t & 15, ty = t >> 4;

  __shared__ float As[16 * 68];
  __shared__ float Bs[16 * 68];

  float acc[16];
#pragma unroll
  for (int p = 0; p < 16; ++p) acc[p] = 0.f;

  const int srow = t >> 2, sf4 = (t & 3) << 2;
  const float* arow = ws + OFF_A + (size_t)(r * 512 + i0 + srow) * 512 + kb;
  const float* brow = ws + OFF_B + (size_t)(r * 512 + j0 + srow) * 512 + kb;

  for (int k0 = 0; k0 < 256; k0 += 16) {
    const float4 av = *(const float4*)(arow + k0 + sf4);
    const float4 bv = *(const float4*)(brow + k0 + sf4);
    __syncthreads();
    As[(sf4 + 0) * 68 + srow] = av.x;
    As[(sf4 + 1) * 68 + srow] = av.y;
    As[(sf4 + 2) * 68 + srow] = av.z;
    As[(sf4 + 3) * 68 + srow] = av.w;
    Bs[(sf4 + 0) * 68 + srow] = bv.x;
    Bs[(sf4 + 1) * 68 + srow] = bv.y;
    Bs[(sf4 + 2) * 68 + srow] = bv.z;
    Bs[(sf4 + 3) * 68 + srow] = bv.w;
    __syncthreads();
#pragma unroll
    for (int k = 0; k < 16; ++k) {
      const float4 a4 = *(const float4*)&As[k * 68 + 4 * ty];
      const float4 b4 = *(const float4*)&Bs[k * 68 + 4 * tx];
      const float av2[4] = {a4.x, a4.y, a4.z, a4.w};
      const float bv2[4] = {b4.x, b4.y, b4.z, b4.w};
#pragma unroll
      for (int c = 0; c < 4; ++c)
#pragma unroll
        for (int d = 0; d < 4; ++d)
          acc[c * 4 + d] = fmaf(av2[c], bv2[d], acc[c * 4 + d]);
    }
  }
  float* dst = ws + OFF_DOT + (size_t)ks * (4 * PLANE) + (size_t)r * PLANE;
#pragma unroll
  for (int c = 0; c < 4; ++c) {
    float4 v;
    v.x = acc[c * 4 + 0]; v.y = acc[c * 4 + 1];
    v.z = acc[c * 4 + 2]; v.w = acc[c * 4 + 3];
    *(float4*)(dst + (size_t)(i0 + 4 * ty + c) * 512 + j0 + 4 * tx) = v;
  }
}

// ---------------- K3: score kernel v6 (abs-trick, 3-op inner) ----------------
// grid 1024 = 16jt x 8it x 4r x 2ks; block 256 (16tx x 16ty; 4i x 2j reg tile).
// relu(hn)*w2 = c*hn + c*|hn| (c=w2/2). Linear half added once via
// Sv*(SA+SB)+CB in the prologue (ks==0 only); per-tuple work is
// u=a+b; hn=fma(u,Sv,beta); acc=fma(c,|hn|,acc)  -- |.| is a free modifier.
__global__ __launch_bounds__(256) void k3_score(float* __restrict__ ws) {
  const int b = blockIdx.x;
  const int jt = b & 15, it = (b >> 4) & 7, r = (b >> 7) & 3, ks = b >> 9;
  const int i0 = it << 6, j0 = jt << 5;
  const int t = threadIdx.x;
  const int tx = t & 15, ty = t >> 4;

  __shared__ float As2[64 * 68];  // [k][i-row swizzled], 64 rows, pitch 68
  __shared__ float Bs2[64 * 36];  // [k][j-row swizzled], 32 rows, pitch 36
  __shared__ float bwS[64 * 2];   // (beta, c) per k of current chunk

  // ---- per-pair LN inverse-sigma Sv[8] (4i x 2j); shift via centering ----
  const float4 mav = *(const float4*)(ws + OFF_MA + r * 512 + i0 + 4 * ty);
  const float4 qav = *(const float4*)(ws + OFF_QA + r * 512 + i0 + 4 * ty);
  const float2 mbv = *(const float2*)(ws + OFF_MB + r * 512 + j0 + 2 * tx);
  const float2 qbv = *(const float2*)(ws + OFF_QB + r * 512 + j0 + 2 * tx);
  const float4 sav = *(const float4*)(ws + OFF_SA + r * 512 + i0 + 4 * ty);
  const float2 sbv = *(const float2*)(ws + OFF_SB + r * 512 + j0 + 2 * tx);
  const float cbr = ws[OFF_CB + r];
  const float mavA[4] = {mav.x, mav.y, mav.z, mav.w};
  const float qavA[4] = {qav.x, qav.y, qav.z, qav.w};
  const float savA[4] = {sav.x, sav.y, sav.z, sav.w};
  const float mbA[2] = {mbv.x, mbv.y};
  const float qbA[2] = {qbv.x, qbv.y};
  const float sbA[2] = {sbv.x, sbv.y};
  float Sv[8], acc[8];
#pragma unroll
  for (int c = 0; c < 4; ++c) {
    const size_t doff = (size_t)r * PLANE + (size_t)(i0 + 4 * ty + c) * 512 + j0 + 2 * tx;
    const float2 d0 = *(const float2*)(ws + OFF_DOT + doff);
    const float2 d1 = *(const float2*)(ws + OFF_DOT + 4 * PLANE + doff);
    const float dA[2] = {d0.x + d1.x, d0.y + d1.y};
#pragma unroll
    for (int d = 0; d < 2; ++d) {
      const int p = c * 2 + d;
      const float mu = mavA[c] + mbA[d];
      const float msq = (qavA[c] + qbA[d] + 2.f * dA[d]) * (1.f / 512.f);
      const float var = msq - mu * mu;
      Sv[p] = 1.0f / sqrtf(var + 1e-5f);   // precise (no fast-math)
      // linear relu-half, added exactly once (ks==0 block)
      acc[p] = (ks == 0) ? fmaf(Sv[p], savA[c] + sbA[d], cbr) : 0.f;
    }
  }

  // ---- staging geometry: thread covers k sf4..sf4+3; A rows ty+16*{0..3},
  //      B rows ty+16*{0,1}. Swizzle: row-group ^= (k>>2)&7 at 16B grain. ----
  const int kbase = ks << 8;
  const int srow = ty;              // 0..15
  const int sf4 = tx << 2;          // 0..60; (k>>2)&7 == tx&7 for staged k
  const int sblk = tx & 7;
  float maR[4], mbR[2];
#pragma unroll
  for (int c2 = 0; c2 < 4; ++c2)
    maR[c2] = ws[OFF_MA + r * 512 + i0 + srow + 16 * c2];
#pragma unroll
  for (int c2 = 0; c2 < 2; ++c2)
    mbR[c2] = ws[OFF_MB + r * 512 + j0 + srow + 16 * c2];

  float4 aC[4], bC[2], gC;
  float2 bwC = make_float2(0.f, 0.f);
  {
    const int kb = kbase;
    gC = *(const float4*)(ws + OFF_G + r * 512 + kb + sf4);
#pragma unroll
    for (int c2 = 0; c2 < 4; ++c2)
      aC[c2] = *(const float4*)(ws + OFF_A + (size_t)(r * 512 + i0 + srow + 16 * c2) * 512 + kb + sf4);
#pragma unroll
    for (int c2 = 0; c2 < 2; ++c2)
      bC[c2] = *(const float4*)(ws + OFF_B + (size_t)(r * 512 + j0 + srow + 16 * c2) * 512 + kb + sf4);
    if (t < 64) bwC = *(const float2*)(ws + OFF_BW + (size_t)(r * 512 + kb + t) * 2);
  }

#pragma unroll
  for (int kc = 0; kc < 4; ++kc) {
    __syncthreads();  // previous chunk's LDS reads complete before overwrite
    // ---- stage current chunk (centered + gamma-scaled), swizzled stores ----
    {
      const float ga[4] = {gC.x, gC.y, gC.z, gC.w};
#pragma unroll
      for (int c2 = 0; c2 < 4; ++c2) {
        const int row = srow + 16 * c2;
        const int off = (((row >> 2) ^ sblk) << 2) + (row & 3);
        const float aq[4] = {aC[c2].x, aC[c2].y, aC[c2].z, aC[c2].w};
#pragma unroll
        for (int q = 0; q < 4; ++q)
          As2[(sf4 + q) * 68 + off] = (aq[q] - maR[c2]) * ga[q];
      }
#pragma unroll
      for (int c2 = 0; c2 < 2; ++c2) {
        const int row = srow + 16 * c2;
        const int off = (((row >> 2) ^ sblk) << 2) + (row & 3);
        const float bq[4] = {bC[c2].x, bC[c2].y, bC[c2].z, bC[c2].w};
#pragma unroll
        for (int q = 0; q < 4; ++q)
          Bs2[(sf4 + q) * 36 + off] = (bq[q] - mbR[c2]) * ga[q];
      }
      if (t < 64) *(float2*)(bwS + 2 * t) = bwC;
    }
    // ---- prefetch next chunk's globals (overlap with compute below) ----
    if (kc < 3) {
      const int kb = kbase + ((kc + 1) << 6);
      gC = *(const float4*)(ws + OFF_G + r * 512 + kb + sf4);
#pragma unroll
      for (int c2 = 0; c2 < 4; ++c2)
        aC[c2] = *(const float4*)(ws + OFF_A + (size_t)(r * 512 + i0 + srow + 16 * c2) * 512 + kb + sf4);
#pragma unroll
      for (int c2 = 0; c2 < 2; ++c2)
        bC[c2] = *(const float4*)(ws + OFF_B + (size_t)(r * 512 + j0 + srow + 16 * c2) * 512 + kb + sf4);
      if (t < 64) bwC = *(const float2*)(ws + OFF_BW + (size_t)(r * 512 + kb + t) * 2);
    }
    __syncthreads();  // staged data visible

    float cacc[8];
#pragma unroll
    for (int p = 0; p < 8; ++p) cacc[p] = 0.f;

#pragma unroll 4
    for (int k = 0; k < 64; ++k) {
      const int K = (k >> 2) & 7;
      const float4 aA = *(const float4*)&As2[k * 68 + ((ty ^ K) << 2)];  // b128
      const float2 bB = *(const float2*)&Bs2[k * 36 + (((tx >> 1) ^ K) << 2) + ((tx & 1) << 1)];  // b64
      const float2 bw = *(const float2*)&bwS[2 * k];                     // b64 broadcast
      const float aq[4] = {aA.x, aA.y, aA.z, aA.w};
      const float bq[2] = {bB.x, bB.y};
#pragma unroll
      for (int c = 0; c < 4; ++c)
#pragma unroll
        for (int d = 0; d < 2; ++d) {
          const int p = c * 2 + d;
          const float u = aq[c] + bq[d];               // (a-ma)g + (b-mb)g
          const float hn = fmaf(u, Sv[p], bw.x);       // *Sv + beta
          cacc[p] = fmaf(bw.y, fabsf(hn), cacc[p]);    // += c*|hn|  (abs free)
        }
    }
    // chunked accumulation: keeps summation error ~2e-7
#pragma unroll
    for (int p = 0; p < 8; ++p) acc[p] += cacc[p];
  }

  float* dst = ws + OFF_S + (size_t)ks * (4 * PLANE) + (size_t)r * PLANE;
#pragma unroll
  for (int c = 0; c < 4; ++c) {
    float2 v;
    v.x = acc[c * 2 + 0];
    v.y = acc[c * 2 + 1];
    *(float2*)(dst + (size_t)(i0 + 4 * ty + c) * 512 + j0 + 2 * tx) = v;
  }
}

// ---------------- K4: combine + outputs ----------------
__global__ __launch_bounds__(256) void k4_combine(const float* __restrict__ ws,
                                                  const float* __restrict__ img,
                                                  const float* __restrict__ txt,
                                                  const float* __restrict__ b2,
                                                  float* __restrict__ out) {
  const int idx = blockIdx.x * 256 + threadIdx.x;  // 0..262143
  const int i = idx >> 9, j = idx & 511;
  const float* s0 = ws + OFF_S;
  const float* s1 = ws + OFF_S + 4 * PLANE;
  float best = -3.4e38f;
  int rel = 0;
#pragma unroll
  for (int r = 0; r < 4; ++r) {
    const float s = s0[r * PLANE + idx] + s1[r * PLANE + idx] + b2[r];
    if (s > best) { best = s; rel = r; }  // strict > == first-index argmax
  }
  out[idx] = (i < 256) ? img[idx] : txt[idx - 131072];
  out[PLANE + idx] = best;
  out[2 * PLANE + idx] = (float)rel;
  // match numpy: float32 best promoted to double vs python-float 0.2
  out[3 * PLANE + idx] = (i != j && (double)best > 0.2) ? 1.0f : 0.0f;
}

extern "C" void kernel_launch(void* const* d_in, const int* in_sizes, int n_in,
                              void* d_out, int out_size, void* d_ws, size_t ws_size,
                              hipStream_t stream) {
  const float* img   = (const float*)d_in[0];
  const float* txt   = (const float*)d_in[1];
  const float* W1    = (const float*)d_in[2];
  const float* b1    = (const float*)d_in[3];
  const float* gamma = (const float*)d_in[4];
  const float* beta  = (const float*)d_in[5];
  const float* w2    = (const float*)d_in[6];
  const float* b2    = (const float*)d_in[7];
  float* ws  = (float*)d_ws;
  float* out = (float*)d_out;
  (void)in_sizes; (void)n_in; (void)out_size; (void)ws_size;

  hipLaunchKernelGGL(k0_gemm,    dim3(512),  dim3(256), 0, stream, img, txt, W1, b1, ws);
  hipLaunchKernelGGL(k1_stats,   dim3(1024), dim3(256), 0, stream, ws, gamma, beta, w2);
  hipLaunchKernelGGL(k2_dot,     dim3(512),  dim3(256), 0, stream, ws);
  hipLaunchKernelGGL(k3_score,   dim3(1024), dim3(256), 0, stream, ws);
  hipLaunchKernelGGL(k4_combine, dim3(1024), dim3(256), 0, stream, ws, img, txt, b2, out);
}